// Round 1
// baseline (115.605 us; speedup 1.0000x reference)
//
#include <hip/hip_runtime.h>

// Pendulum2 constrained-dynamics DAE forward, fully closed-form per element.
// m = [1, 50], l = [1, 1], g = 10  ->  minv = [1,1,0.02,0.02], F = [0,-10,0,-500].
//
// Per row (x0,y0,x1,y1,u0,w0,u1,w1):
//   dx=x0-x1, dy=y0-y1, du=u0-u1, dw=w0-w1
//   L11 = 4(x0^2+y0^2)
//   L12 = 4(x0*dx + y0*dy)
//   L22 = 4*1.02*(dx^2+dy^2)
//   R1  = -20*y0 + 2(u0^2+w0^2)
//   R2  =  2(du^2+dw^2)            (gravity terms cancel exactly)
//   [lam1,lam2] = inv([[L11,L12],[L12,L22]]) @ [R1,R2]
//   a0 = -2(x0*lam1 + dx*lam2)
//   a1 = -10 - 2(y0*lam1 + dy*lam2)
//   a2 =  0.04*dx*lam2
//   a3 = -10 + 0.04*dy*lam2
// Output row = [u0,w0,u1,w1, a0,a1,a2,a3].

__global__ __launch_bounds__(256) void pend2_dae_kernel(
    const float4* __restrict__ in,   // coords as float4 pairs: [2*n] float4
    float4* __restrict__ out,        // same layout
    int n)                           // number of batch rows
{
    int i = blockIdx.x * blockDim.x + threadIdx.x;
    if (i >= n) return;

    float4 p = in[2 * i];       // x0, y0, x1, y1
    float4 q = in[2 * i + 1];   // u0, w0, u1, w1

    float x0 = p.x, y0 = p.y, x1 = p.z, y1 = p.w;
    float u0 = q.x, w0 = q.y, u1 = q.z, w1 = q.w;

    float dx = x0 - x1, dy = y0 - y1;
    float du = u0 - u1, dw = w0 - w1;

    float L11 = 4.0f * (x0 * x0 + y0 * y0);
    float L12 = 4.0f * (x0 * dx + y0 * dy);
    float L22 = 4.08f * (dx * dx + dy * dy);   // 4 * (1 + 1/50) * |d|^2

    float R1 = -20.0f * y0 + 2.0f * (u0 * u0 + w0 * w0);
    float R2 = 2.0f * (du * du + dw * dw);

    float det = L11 * L22 - L12 * L12;
    float inv = 1.0f / det;
    float lam1 = (L22 * R1 - L12 * R2) * inv;
    float lam2 = (L11 * R2 - L12 * R1) * inv;

    float a0 = -2.0f * (x0 * lam1 + dx * lam2);
    float a1 = -10.0f - 2.0f * (y0 * lam1 + dy * lam2);
    float a2 = 0.04f * dx * lam2;
    float a3 = -10.0f + 0.04f * dy * lam2;

    out[2 * i]     = q;                              // velocities pass through
    out[2 * i + 1] = make_float4(a0, a1, a2, a3);    // accelerations
}

extern "C" void kernel_launch(void* const* d_in, const int* in_sizes, int n_in,
                              void* d_out, int out_size, void* d_ws, size_t ws_size,
                              hipStream_t stream) {
    // d_in[0] = t (unused, autonomous system), d_in[1] = coords [bs, 8] fp32
    const float4* coords = (const float4*)d_in[1];
    float4* out = (float4*)d_out;
    int n = in_sizes[1] / 8;   // batch rows

    int block = 256;
    int grid = (n + block - 1) / block;
    pend2_dae_kernel<<<grid, block, 0, stream>>>(coords, out, n);
}

// Round 2
// 109.719 us; speedup vs baseline: 1.0536x; 1.0536x over previous
//
#include <hip/hip_runtime.h>

// Pendulum2 constrained-dynamics DAE forward, closed-form per row.
// m = [1, 50], l = [1, 1], g = 10  ->  minv = [1,1,0.02,0.02].
//
// Fully-coalesced variant: one thread per float4 (half-row). Thread j loads
// in[j] (unit stride, 16 B/lane), exchanges with lane partner (j^1) via
// __shfl_xor so both lanes of the pair hold the complete row (p = positions,
// q = velocities). Both lanes redundantly compute the 2x2 constraint solve
// (~30 FLOPs — free, we're memory-bound), then:
//   even lane (j = 2r)   writes out[j] = q          (velocity passthrough)
//   odd  lane (j = 2r+1) writes out[j] = accelerations
// Stores are unit-stride and non-temporal (streaming write, no reuse).

typedef float vfloat4_t __attribute__((ext_vector_type(4)));

__global__ __launch_bounds__(256) void pend2_dae_kernel(
    const float4* __restrict__ in,   // coords as float4s: [2*n_rows]
    float4* __restrict__ out,        // same layout
    int n4)                          // number of float4s = 2*n_rows
{
    int j = blockIdx.x * blockDim.x + threadIdx.x;
    if (j >= n4) return;

    float4 mine = in[j];

    // Exchange with lane partner (pairs are lane (2k, 2k+1); blockDim is even
    // so float4-index parity == lane parity).
    float4 other;
    other.x = __shfl_xor(mine.x, 1);
    other.y = __shfl_xor(mine.y, 1);
    other.z = __shfl_xor(mine.z, 1);
    other.w = __shfl_xor(mine.w, 1);

    bool odd = (j & 1);
    float4 p = odd ? other : mine;   // x0, y0, x1, y1 (even float4 of the row)
    float4 q = odd ? mine : other;   // u0, w0, u1, w1 (odd  float4 of the row)

    float x0 = p.x, y0 = p.y, x1 = p.z, y1 = p.w;
    float u0 = q.x, w0 = q.y, u1 = q.z, w1 = q.w;

    float dx = x0 - x1, dy = y0 - y1;
    float du = u0 - u1, dw = w0 - w1;

    float L11 = 4.0f * (x0 * x0 + y0 * y0);
    float L12 = 4.0f * (x0 * dx + y0 * dy);
    float L22 = 4.08f * (dx * dx + dy * dy);   // 4 * (1 + 1/50) * |d|^2

    float R1 = -20.0f * y0 + 2.0f * (u0 * u0 + w0 * w0);
    float R2 = 2.0f * (du * du + dw * dw);     // gravity terms cancel exactly

    float det = L11 * L22 - L12 * L12;
    float inv = 1.0f / det;
    float lam1 = (L22 * R1 - L12 * R2) * inv;
    float lam2 = (L11 * R2 - L12 * R1) * inv;

    vfloat4_t res;
    if (odd) {
        res.x = -2.0f * (x0 * lam1 + dx * lam2);
        res.y = -10.0f - 2.0f * (y0 * lam1 + dy * lam2);
        res.z = 0.04f * dx * lam2;
        res.w = -10.0f + 0.04f * dy * lam2;
    } else {
        res.x = q.x; res.y = q.y; res.z = q.z; res.w = q.w;
    }

    __builtin_nontemporal_store(res, (vfloat4_t*)&out[j]);
}

extern "C" void kernel_launch(void* const* d_in, const int* in_sizes, int n_in,
                              void* d_out, int out_size, void* d_ws, size_t ws_size,
                              hipStream_t stream) {
    // d_in[0] = t (unused, autonomous system), d_in[1] = coords [bs, 8] fp32
    const float4* coords = (const float4*)d_in[1];
    float4* out = (float4*)d_out;
    int n4 = in_sizes[1] / 4;   // total float4s (= 2 * batch rows)

    int block = 256;
    int grid = (n4 + block - 1) / block;
    pend2_dae_kernel<<<grid, block, 0, stream>>>(coords, out, n4);
}